// Round 9
// baseline (1275.302 us; speedup 1.0000x reference)
//
#include <hip/hip_runtime.h>
#include <hip/hip_bf16.h>
#include <stdint.h>

typedef __attribute__((ext_vector_type(8))) short short8;   // 8 bf16 = 4 VGPR (MFMA A/B frag)
typedef __attribute__((ext_vector_type(4))) short short4v;  // 4 bf16
typedef __attribute__((ext_vector_type(4))) float f32x4;    // MFMA C/D frag
typedef __attribute__((ext_vector_type(4))) int   i32x4;

#define MFMA16(a, b, c) __builtin_amdgcn_mfma_f32_16x16x32_bf16((a), (b), (c), 0, 0, 0)

static __device__ __forceinline__ short f2bf(float f) {
    union { float f; uint32_t i; } v; v.f = f;
    uint32_t r = v.i + 0x7fffu + ((v.i >> 16) & 1u);  // RNE
    return (short)(r >> 16);
}

// pack 2 f32 -> 1 u32 of 2 bf16 (lo=a, hi=b), single HW op (T12 recipe)
static __device__ __forceinline__ int cvtpk(float a, float b) {
    int r;
    asm("v_cvt_pk_bf16_f32 %0, %1, %2" : "=v"(r) : "v"(a), "v"(b));
    return r;
}

// ---------------- elementwise f32 -> bf16 (vectorized, G13) ----------------
__global__ void conv_f32_bf16(const float* __restrict__ in, short* __restrict__ out, int n4) {
    int i = blockIdx.x * blockDim.x + threadIdx.x;
    int stride = gridDim.x * blockDim.x;
    for (; i < n4; i += stride) {
        f32x4 v = *(const f32x4*)(in + (size_t)i * 4);
        short4v o;
        o[0] = f2bf(v[0]); o[1] = f2bf(v[1]); o[2] = f2bf(v[2]); o[3] = f2bf(v[3]);
        *(short4v*)(out + (size_t)i * 4) = o;
    }
}

// ------------- transpose + convert: W[R][C] f32 -> Wt[C][R] bf16 -------------
__global__ void conv_transpose(const float* __restrict__ W, short* __restrict__ Wt, int R, int C) {
    __shared__ float tile[32][33];
    int c0 = blockIdx.x * 32;
    int r0 = blockIdx.y * 32;
    int tx = threadIdx.x;   // 0..31
    int ty = threadIdx.y;   // 0..7
    for (int j = 0; j < 4; ++j) {
        int r = ty * 4 + j;
        tile[r][tx] = W[(size_t)(r0 + r) * C + c0 + tx];
    }
    __syncthreads();
    for (int j = 0; j < 4; ++j) {
        int c = ty * 4 + j;
        Wt[(size_t)(c0 + c) * R + r0 + tx] = f2bf(tile[tx][c]);
    }
}

// ---------------- QKV GEMM ----------------
// Q pre-scaled by log2(e)/8. V: coalesced to Vc[BH][T][64] when Vc!=null
// (v_transpose then builds the k-permuted V^T); else legacy scatter.
__global__ __launch_bounds__(256) void gemm_qkv(
    const short* __restrict__ A, const short* __restrict__ Bt,
    const float* __restrict__ bias,
    short* __restrict__ Qg, short* __restrict__ Kg, short* __restrict__ Vg,
    short* __restrict__ Vc)
{
    const int K = 1024;
    __shared__ short As[128 * 32];
    __shared__ short Bs[128 * 32];
    const int tid = threadIdx.x, lane = tid & 63, wid = tid >> 6;
    const int wr = wid >> 1, wc = wid & 1;
    const int m0 = blockIdx.y * 128, n0 = blockIdx.x * 128;
    const int l15 = lane & 15, l4 = lane >> 4;

    f32x4 acc[4][4] = {};

    int rowS[2], ugS[2];
    for (int t = 0; t < 2; ++t) {
        int c = tid + t * 256;
        rowS[t] = c >> 2;
        ugS[t] = (c & 3) ^ ((rowS[t] >> 1) & 3);
    }
    int offA[4], offB[4];
    for (int f = 0; f < 4; ++f) {
        int ra = wr * 64 + f * 16 + l15;
        offA[f] = ra * 32 + ((l4 ^ ((ra >> 1) & 3)) * 8);
        int rb = wc * 64 + f * 16 + l15;
        offB[f] = rb * 32 + ((l4 ^ ((rb >> 1) & 3)) * 8);
    }

    for (int k0 = 0; k0 < K; k0 += 32) {
        __syncthreads();
        for (int t = 0; t < 2; ++t) {
            const short* ga = A  + (size_t)(m0 + rowS[t]) * K + k0 + ugS[t] * 8;
            const short* gb = Bt + (size_t)(n0 + rowS[t]) * K + k0 + ugS[t] * 8;
            short* la = As + (t * 256 + wid * 64) * 8;
            short* lb = Bs + (t * 256 + wid * 64) * 8;
            __builtin_amdgcn_global_load_lds((const __attribute__((address_space(1))) void*)ga,
                                             (__attribute__((address_space(3))) void*)la, 16, 0, 0);
            __builtin_amdgcn_global_load_lds((const __attribute__((address_space(1))) void*)gb,
                                             (__attribute__((address_space(3))) void*)lb, 16, 0, 0);
        }
        __syncthreads();
        short8 a[4], b[4];
        for (int f = 0; f < 4; ++f) a[f] = *(const short8*)&As[offA[f]];
        for (int f = 0; f < 4; ++f) b[f] = *(const short8*)&Bs[offB[f]];
        for (int mf = 0; mf < 4; ++mf)
            for (int nf = 0; nf < 4; ++nf)
                acc[mf][nf] = MFMA16(a[mf], b[nf], acc[mf][nf]);
    }

    // epilogue: Q[BH][T][64] (x log2e/8), K[BH][T][64], V coalesced or scatter
    for (int mf = 0; mf < 4; ++mf) {
        int grow_base = m0 + wr * 64 + mf * 16 + l4 * 4;
        for (int nf = 0; nf < 4; ++nf) {
            int gcol = n0 + wc * 64 + nf * 16 + l15;
            float bb = bias[gcol];
            int which = gcol >> 10, rem = gcol & 1023;
            int h = rem >> 6, d = rem & 63;
            for (int r = 0; r < 4; ++r) {
                int grow = grow_base + r;
                int b = grow >> 11, t = grow & 2047;
                int bh = (b << 4) + h;
                float val = acc[mf][nf][r] + bb;
                if (which == 0) val *= 0.18033688011112042f;  // log2e/8
                short bv = f2bf(val);
                if (which == 0)      Qg[((size_t)bh * 2048 + t) * 64 + d] = bv;
                else if (which == 1) Kg[((size_t)bh * 2048 + t) * 64 + d] = bv;
                else if (Vc)         Vc[((size_t)bh * 2048 + t) * 64 + d] = bv;
                else {
                    int k6 = t & 63;
                    int pos = (k6 & 32) + ((k6 & 12) << 1) + ((k6 & 16) >> 2) + (k6 & 3);
                    Vg[((size_t)bh * 64 + d) * 2048 + (t & ~63) + pos] = bv;
                }
            }
        }
    }
}

// -------- V transpose: Vc[BH][T][64] -> Vg[BH][64][T] with k-permutation --------
// pos p = 32c+8a+4b+m  <->  k6 = 32c+16b+4a+m   (matches attn's PV k-order)
__global__ __launch_bounds__(256) void v_transpose(const short* __restrict__ Vc,
                                                   short* __restrict__ Vg) {
    __shared__ short tile[64][72];   // +8 pad, 16B-aligned rows
    const int tid = threadIdx.x;
    const int bh = blockIdx.y;
    const int t0 = blockIdx.x * 64;
    {
        int tt = tid >> 2, q = (tid & 3) * 16;
        const short* src = Vc + ((size_t)bh * 2048 + t0 + tt) * 64 + q;
        *(short8*)&tile[tt][q]     = *(const short8*)&src[0];
        *(short8*)&tile[tt][q + 8] = *(const short8*)&src[8];
    }
    __syncthreads();
    {
        int d = tid >> 2, pc = (tid & 3) * 16;
        short8 o0, o1;
        #pragma unroll
        for (int i = 0; i < 16; ++i) {
            int p = pc + i;
            int k6 = (p & 32) + ((p & 4) << 2) + ((p >> 1) & 12) + (p & 3);
            short v = tile[k6][d];
            if (i < 8) o0[i] = v; else o1[i - 8] = v;
        }
        short* dst = Vg + ((size_t)bh * 64 + d) * 2048 + t0 + pc;
        *(short8*)&dst[0] = o0;
        *(short8*)&dst[8] = o1;
    }
}

// ---------------- flash attention: swapped-QK^T, zero-LDS + K-prefetch ----------------
// R8 structure (swapped QK^T, in-lane P via cvt_pk, memory-permuted V, exp2,
// no LDS, no barriers) + this round:
//  (a) K ping-pong prefetch: tile j+1's K loads issued BEFORE tile j's V loads.
//      vmcnt is FIFO -> the V-wait before PV subsumes next-K's wait, so the
//      QK cluster never stalls on loads after tile 0. +32 VGPR (~155 total).
//  (b) s_setprio(1) around MFMA clusters (m191 regime: independent waves).
#define LOADK(KB, KV0) do {                                                                     \
    _Pragma("unroll")                                                                           \
    for (int kf_ = 0; kf_ < 4; ++kf_) {                                                         \
        KB[kf_][0] = *(const short8*)&Kh[(size_t)((KV0) + kf_ * 16 + l15) * 64 + l4 * 8];       \
        KB[kf_][1] = *(const short8*)&Kh[(size_t)((KV0) + kf_ * 16 + l15) * 64 + 32 + l4 * 8];  \
    }                                                                                           \
} while (0)

#define LOADV(VB, KV0) do {                                                                     \
    _Pragma("unroll")                                                                           \
    for (int df_ = 0; df_ < 4; ++df_) {                                                         \
        VB[df_][0] = *(const short8*)&Vh[(size_t)(df_ * 16 + l15) * 2048 + (KV0) + l4 * 8];     \
        VB[df_][1] = *(const short8*)&Vh[(size_t)(df_ * 16 + l15) * 2048 + (KV0) + 32 + l4 * 8];\
    }                                                                                           \
} while (0)

#define TILE(KB, KV0) do {                                                                      \
    const bool diag_ = ((KV0) == (nt - 1) * 64);                                                \
    _Pragma("unroll")                                                                           \
    for (int h_ = 0; h_ < 2; ++h_) {                                                            \
        f32x4 sf_[4];                                                                           \
        __builtin_amdgcn_s_setprio(1);                                                          \
        _Pragma("unroll")                                                                       \
        for (int kf_ = 0; kf_ < 4; ++kf_) {                                                     \
            f32x4 z_ = {};                                                                      \
            z_ = MFMA16(KB[kf_][0], qf[h_][0], z_);                                             \
            z_ = MFMA16(KB[kf_][1], qf[h_][1], z_);                                             \
            sf_[kf_] = z_;                                                                      \
        }                                                                                       \
        __builtin_amdgcn_s_setprio(0);                                                          \
        const int gq_ = q0 + h_ * 16 + l15;                                                     \
        int w_[4][2];                                                                           \
        _Pragma("unroll")                                                                       \
        for (int kf_ = 0; kf_ < 4; ++kf_) {                                                     \
            float pf_[4];                                                                       \
            _Pragma("unroll")                                                                   \
            for (int r_ = 0; r_ < 4; ++r_) {                                                    \
                float v_ = sf_[kf_][r_];                                                        \
                if (diag_ && ((KV0) + kf_ * 16 + l4 * 4 + r_) > gq_) v_ = -1e9f;                \
                float pp_ = exp2f(v_);                                                          \
                lsum[h_] += pp_;                                                                \
                pf_[r_] = pp_;                                                                  \
            }                                                                                   \
            w_[kf_][0] = cvtpk(pf_[0], pf_[1]);                                                 \
            w_[kf_][1] = cvtpk(pf_[2], pf_[3]);                                                 \
        }                                                                                       \
        union { i32x4 i; short8 s8; } pa0_, pa1_;                                               \
        pa0_.i[0] = w_[0][0]; pa0_.i[1] = w_[0][1]; pa0_.i[2] = w_[1][0]; pa0_.i[3] = w_[1][1]; \
        pa1_.i[0] = w_[2][0]; pa1_.i[1] = w_[2][1]; pa1_.i[2] = w_[3][0]; pa1_.i[3] = w_[3][1]; \
        __builtin_amdgcn_s_setprio(1);                                                          \
        _Pragma("unroll")                                                                       \
        for (int df_ = 0; df_ < 4; ++df_) {                                                     \
            o[h_][df_] = MFMA16(pa0_.s8, vb[df_][0], o[h_][df_]);                               \
            o[h_][df_] = MFMA16(pa1_.s8, vb[df_][1], o[h_][df_]);                               \
        }                                                                                       \
        __builtin_amdgcn_s_setprio(0);                                                          \
    }                                                                                           \
} while (0)

__global__ __launch_bounds__(256) void attn_kernel(
    const short* __restrict__ Qg, const short* __restrict__ Kg, const short* __restrict__ Vg,
    short* __restrict__ AO)
{
    const int tid = threadIdx.x, lane = tid & 63, wid = tid >> 6;
    const int l15 = lane & 15, l4 = lane >> 4;
    const int bp = blockIdx.x;            // 0..511
    const int xcd = bp & 7, slot = bp >> 3;   // slot 0..63
    const int bh = xcd * 8 + (slot >> 3);     // 8 heads per XCD (L2 pinning)
    const int iblk = slot & 7;
    const int pr = iblk * 4 + wid;        // pair index 0..31
    const short* Qh = Qg + (size_t)bh * 2048 * 64;
    const short* Kh = Kg + (size_t)bh * 2048 * 64;
    const short* Vh = Vg + (size_t)bh * 64 * 2048;
    const int b = bh >> 4, head = bh & 15;

    for (int half = 0; half < 2; ++half) {
        const int s = half ? (63 - pr) : pr;  // strip 0..63
        const int q0 = s * 32;
        const int nt = (s >> 1) + 1;

        short8 qf[2][2];
        #pragma unroll
        for (int h = 0; h < 2; ++h)
            #pragma unroll
            for (int c = 0; c < 2; ++c)
                qf[h][c] = *(const short8*)&Qh[(size_t)(q0 + h * 16 + l15) * 64 + c * 32 + l4 * 8];

        f32x4 o[2][4] = {};
        float lsum[2] = { 0.f, 0.f };

        short8 kb0[4][2], kb1[4][2], vb[4][2];
        LOADK(kb0, 0);
        int j = 0;
        for (;;) {
            {
                const int kv0 = j * 64;
                if (j + 1 < nt) LOADK(kb1, kv0 + 64);   // issue BEFORE V loads
                LOADV(vb, kv0);
                TILE(kb0, kv0);
            }
            if (++j == nt) break;
            {
                const int kv0 = j * 64;
                if (j + 1 < nt) LOADK(kb0, kv0 + 64);
                LOADV(vb, kv0);
                TILE(kb1, kv0);
            }
            if (++j == nt) break;
        }

        // lsum: sum the 4 k-slice partials (lanes differing in l4)
        #pragma unroll
        for (int h = 0; h < 2; ++h) {
            lsum[h] += __shfl_xor(lsum[h], 16, 64);
            lsum[h] += __shfl_xor(lsum[h], 32, 64);
        }

        // epilogue: O frag is lane -> O[q=l4*4+r][d=df*16+l15]; inv from lane q
        #pragma unroll
        for (int h = 0; h < 2; ++h)
            #pragma unroll
            for (int r = 0; r < 4; ++r) {
                float inv = 1.0f / __shfl(lsum[h], l4 * 4 + r, 64);
                size_t grow = (size_t)b * 2048 + q0 + h * 16 + l4 * 4 + r;
                #pragma unroll
                for (int df = 0; df < 4; ++df)
                    AO[grow * 1024 + head * 64 + df * 16 + l15] = f2bf(o[h][df][r] * inv);
            }
    }
}

// ---------------- out GEMM: AO[8192][1024] @ WoutT[1024][1024]^T + bout -> f32 ----------------
__global__ __launch_bounds__(256) void gemm_out(
    const short* __restrict__ A, const short* __restrict__ Bt,
    const float* __restrict__ bias, float* __restrict__ out)
{
    const int K = 1024;
    __shared__ short As[128 * 32];
    __shared__ short Bs[128 * 32];
    const int tid = threadIdx.x, lane = tid & 63, wid = tid >> 6;
    const int wr = wid >> 1, wc = wid & 1;
    const int m0 = blockIdx.y * 128, n0 = blockIdx.x * 128;
    const int l15 = lane & 15, l4 = lane >> 4;

    f32x4 acc[4][4] = {};

    int rowS[2], ugS[2];
    for (int t = 0; t < 2; ++t) {
        int c = tid + t * 256;
        rowS[t] = c >> 2;
        ugS[t] = (c & 3) ^ ((rowS[t] >> 1) & 3);
    }
    int offA[4], offB[4];
    for (int f = 0; f < 4; ++f) {
        int ra = wr * 64 + f * 16 + l15;
        offA[f] = ra * 32 + ((l4 ^ ((ra >> 1) & 3)) * 8);
        int rb = wc * 64 + f * 16 + l15;
        offB[f] = rb * 32 + ((l4 ^ ((rb >> 1) & 3)) * 8);
    }

    for (int k0 = 0; k0 < K; k0 += 32) {
        __syncthreads();
        for (int t = 0; t < 2; ++t) {
            const short* ga = A  + (size_t)(m0 + rowS[t]) * K + k0 + ugS[t] * 8;
            const short* gb = Bt + (size_t)(n0 + rowS[t]) * K + k0 + ugS[t] * 8;
            short* la = As + (t * 256 + wid * 64) * 8;
            short* lb = Bs + (t * 256 + wid * 64) * 8;
            __builtin_amdgcn_global_load_lds((const __attribute__((address_space(1))) void*)ga,
                                             (__attribute__((address_space(3))) void*)la, 16, 0, 0);
            __builtin_amdgcn_global_load_lds((const __attribute__((address_space(1))) void*)gb,
                                             (__attribute__((address_space(3))) void*)lb, 16, 0, 0);
        }
        __syncthreads();
        short8 a[4], b[4];
        for (int f = 0; f < 4; ++f) a[f] = *(const short8*)&As[offA[f]];
        for (int f = 0; f < 4; ++f) b[f] = *(const short8*)&Bs[offB[f]];
        for (int mf = 0; mf < 4; ++mf)
            for (int nf = 0; nf < 4; ++nf)
                acc[mf][nf] = MFMA16(a[mf], b[nf], acc[mf][nf]);
    }

    for (int mf = 0; mf < 4; ++mf) {
        int grow_base = m0 + wr * 64 + mf * 16 + l4 * 4;
        for (int nf = 0; nf < 4; ++nf) {
            int gcol = n0 + wc * 64 + nf * 16 + l15;
            float bb = bias[gcol];
            for (int r = 0; r < 4; ++r) {
                int grow = grow_base + r;
                out[(size_t)grow * 1024 + gcol] = acc[mf][nf][r] + bb;
            }
        }
    }
}

extern "C" void kernel_launch(void* const* d_in, const int* in_sizes, int n_in,
                              void* d_out, int out_size, void* d_ws, size_t ws_size,
                              hipStream_t stream) {
    (void)in_sizes; (void)n_in; (void)out_size;
    const float* x    = (const float*)d_in[0];
    // d_in[1] = attn_mask (causal by construction; applied analytically)
    const float* Wqkv = (const float*)d_in[2];
    const float* bqkv = (const float*)d_in[3];
    const float* Wout = (const float*)d_in[4];
    const float* bout = (const float*)d_in[5];
    float* out = (float*)d_out;

    char* ws = (char*)d_ws;
    short* xb    = (short*)(ws);                         // 16 MB [8192][1024]
    short* WqkvT = (short*)(ws + (16ull << 20));         //  6 MB [3072][1024]
    short* WoutT = (short*)(ws + (22ull << 20));         //  2 MB [1024][1024]
    short* Qg    = (short*)(ws + (24ull << 20));         // 16 MB [64][2048][64]
    short* Kg    = (short*)(ws + (40ull << 20));         // 16 MB [64][2048][64]
    short* Vg    = (short*)(ws + (56ull << 20));         // 16 MB [64][64][2048] (k-permuted)
    short* AO    = xb;                                   // reuse (xb dead after gemm_qkv)

    // V staging buffer only if workspace allows; else proven scatter path.
    const bool coal = ws_size >= (88ull << 20);
    short* Vc = coal ? (short*)(ws + (72ull << 20)) : (short*)nullptr;   // 16 MB

    conv_f32_bf16<<<2048, 256, 0, stream>>>(x, xb, 8192 * 1024 / 4);
    conv_transpose<<<dim3(3072 / 32, 1024 / 32), dim3(32, 8), 0, stream>>>(Wqkv, WqkvT, 1024, 3072);
    conv_transpose<<<dim3(1024 / 32, 1024 / 32), dim3(32, 8), 0, stream>>>(Wout, WoutT, 1024, 1024);
    gemm_qkv<<<dim3(24, 64), 256, 0, stream>>>(xb, WqkvT, bqkv, Qg, Kg, Vg, Vc);
    if (coal) v_transpose<<<dim3(32, 64), 256, 0, stream>>>(Vc, Vg);
    attn_kernel<<<512, 256, 0, stream>>>(Qg, Kg, Vg, AO);
    gemm_out<<<dim3(8, 64), 256, 0, stream>>>(AO, WoutT, bout, out);
}

// Round 10
// 344.239 us; speedup vs baseline: 3.7047x; 3.7047x over previous
//
#include <hip/hip_runtime.h>
#include <hip/hip_bf16.h>
#include <stdint.h>

typedef __attribute__((ext_vector_type(8))) short short8;   // 8 bf16 = 4 VGPR (MFMA A/B frag)
typedef __attribute__((ext_vector_type(4))) short short4v;  // 4 bf16
typedef __attribute__((ext_vector_type(4))) float f32x4;    // MFMA C/D frag
typedef __attribute__((ext_vector_type(4))) int   i32x4;

#define MFMA16(a, b, c) __builtin_amdgcn_mfma_f32_16x16x32_bf16((a), (b), (c), 0, 0, 0)

static __device__ __forceinline__ short f2bf(float f) {
    union { float f; uint32_t i; } v; v.f = f;
    uint32_t r = v.i + 0x7fffu + ((v.i >> 16) & 1u);  // RNE
    return (short)(r >> 16);
}

// pack 2 f32 -> 1 u32 of 2 bf16 (lo=a, hi=b), single HW op (T12 recipe)
static __device__ __forceinline__ int cvtpk(float a, float b) {
    int r;
    asm("v_cvt_pk_bf16_f32 %0, %1, %2" : "=v"(r) : "v"(a), "v"(b));
    return r;
}

// ---------------- elementwise f32 -> bf16 (vectorized, G13) ----------------
__global__ void conv_f32_bf16(const float* __restrict__ in, short* __restrict__ out, int n4) {
    int i = blockIdx.x * blockDim.x + threadIdx.x;
    int stride = gridDim.x * blockDim.x;
    for (; i < n4; i += stride) {
        f32x4 v = *(const f32x4*)(in + (size_t)i * 4);
        short4v o;
        o[0] = f2bf(v[0]); o[1] = f2bf(v[1]); o[2] = f2bf(v[2]); o[3] = f2bf(v[3]);
        *(short4v*)(out + (size_t)i * 4) = o;
    }
}

// ------------- transpose + convert: W[R][C] f32 -> Wt[C][R] bf16 -------------
__global__ void conv_transpose(const float* __restrict__ W, float* __restrict__ /*unused*/, short* __restrict__ Wt, int R, int C);
__global__ void conv_transpose2(const float* __restrict__ W, short* __restrict__ Wt, int R, int C) {
    __shared__ float tile[32][33];
    int c0 = blockIdx.x * 32;
    int r0 = blockIdx.y * 32;
    int tx = threadIdx.x;   // 0..31
    int ty = threadIdx.y;   // 0..7
    for (int j = 0; j < 4; ++j) {
        int r = ty * 4 + j;
        tile[r][tx] = W[(size_t)(r0 + r) * C + c0 + tx];
    }
    __syncthreads();
    for (int j = 0; j < 4; ++j) {
        int c = ty * 4 + j;
        Wt[(size_t)(c0 + c) * R + r0 + tx] = f2bf(tile[tx][c]);
    }
}

// ---------------- QKV GEMM: xb[8192][1024] @ WqkvT[3072][1024]^T ----------------
// EXACT R8 version (compile-time single epilogue path — R9's runtime Vc branch
// made hipcc demote acc[4][4] to scratch: VGPR 32, 5GB traffic, 1008us. Never
// put runtime-selected output paths in a hot MFMA epilogue.)
// Q pre-scaled by log2(e)/8; V stored k-permuted within each 64-row tile:
// k -> pos = 32c+8a+4b+m (k = 32c+16b+4a+m) to match attn's in-lane P k-order.
__global__ __launch_bounds__(256) void gemm_qkv(
    const short* __restrict__ A, const short* __restrict__ Bt,
    const float* __restrict__ bias,
    short* __restrict__ Qg, short* __restrict__ Kg, short* __restrict__ Vg)
{
    const int K = 1024;
    __shared__ short As[128 * 32];
    __shared__ short Bs[128 * 32];
    const int tid = threadIdx.x, lane = tid & 63, wid = tid >> 6;
    const int wr = wid >> 1, wc = wid & 1;
    const int m0 = blockIdx.y * 128, n0 = blockIdx.x * 128;
    const int l15 = lane & 15, l4 = lane >> 4;

    f32x4 acc[4][4] = {};

    int rowS[2], ugS[2];
    for (int t = 0; t < 2; ++t) {
        int c = tid + t * 256;
        rowS[t] = c >> 2;
        ugS[t] = (c & 3) ^ ((rowS[t] >> 1) & 3);
    }
    int offA[4], offB[4];
    for (int f = 0; f < 4; ++f) {
        int ra = wr * 64 + f * 16 + l15;
        offA[f] = ra * 32 + ((l4 ^ ((ra >> 1) & 3)) * 8);
        int rb = wc * 64 + f * 16 + l15;
        offB[f] = rb * 32 + ((l4 ^ ((rb >> 1) & 3)) * 8);
    }

    for (int k0 = 0; k0 < K; k0 += 32) {
        __syncthreads();
        for (int t = 0; t < 2; ++t) {
            const short* ga = A  + (size_t)(m0 + rowS[t]) * K + k0 + ugS[t] * 8;
            const short* gb = Bt + (size_t)(n0 + rowS[t]) * K + k0 + ugS[t] * 8;
            short* la = As + (t * 256 + wid * 64) * 8;
            short* lb = Bs + (t * 256 + wid * 64) * 8;
            __builtin_amdgcn_global_load_lds((const __attribute__((address_space(1))) void*)ga,
                                             (__attribute__((address_space(3))) void*)la, 16, 0, 0);
            __builtin_amdgcn_global_load_lds((const __attribute__((address_space(1))) void*)gb,
                                             (__attribute__((address_space(3))) void*)lb, 16, 0, 0);
        }
        __syncthreads();
        short8 a[4], b[4];
        for (int f = 0; f < 4; ++f) a[f] = *(const short8*)&As[offA[f]];
        for (int f = 0; f < 4; ++f) b[f] = *(const short8*)&Bs[offB[f]];
        for (int mf = 0; mf < 4; ++mf)
            for (int nf = 0; nf < 4; ++nf)
                acc[mf][nf] = MFMA16(a[mf], b[nf], acc[mf][nf]);
    }

    // epilogue: Q[BH][T][64] (x log2e/8), K[BH][T][64], V permuted [BH][64][T]
    for (int mf = 0; mf < 4; ++mf) {
        int grow_base = m0 + wr * 64 + mf * 16 + l4 * 4;
        for (int nf = 0; nf < 4; ++nf) {
            int gcol = n0 + wc * 64 + nf * 16 + l15;
            float bb = bias[gcol];
            int which = gcol >> 10, rem = gcol & 1023;
            int h = rem >> 6, d = rem & 63;
            for (int r = 0; r < 4; ++r) {
                int grow = grow_base + r;
                int b = grow >> 11, t = grow & 2047;
                int bh = (b << 4) + h;
                float val = acc[mf][nf][r] + bb;
                if (which == 0) val *= 0.18033688011112042f;  // log2e/8
                short bv = f2bf(val);
                if (which == 0)      Qg[((size_t)bh * 2048 + t) * 64 + d] = bv;
                else if (which == 1) Kg[((size_t)bh * 2048 + t) * 64 + d] = bv;
                else {
                    int k6 = t & 63;
                    int pos = (k6 & 32) + ((k6 & 12) << 1) + ((k6 & 16) >> 2) + (k6 & 3);
                    Vg[((size_t)bh * 64 + d) * 2048 + (t & ~63) + pos] = bv;
                }
            }
        }
    }
}

// ---------------- flash attention: swapped-QK^T, zero-LDS + K-prefetch ----------------
// R8 structure (swapped QK^T, in-lane P via cvt_pk, memory-permuted V, exp2,
// no LDS, no barriers) + R9 additions (this round's isolated A/B vs R8 132.6us):
//  (a) K ping-pong prefetch: tile j+1's K loads issued BEFORE tile j's V loads.
//      vmcnt is FIFO -> the V-wait before PV subsumes next-K's wait, so the
//      QK cluster never stalls on loads after tile 0. +32 VGPR (~155 total).
//  (b) s_setprio(1) around MFMA clusters (m191 regime: independent waves).
#define LOADK(KB, KV0) do {                                                                     \
    _Pragma("unroll")                                                                           \
    for (int kf_ = 0; kf_ < 4; ++kf_) {                                                         \
        KB[kf_][0] = *(const short8*)&Kh[(size_t)((KV0) + kf_ * 16 + l15) * 64 + l4 * 8];       \
        KB[kf_][1] = *(const short8*)&Kh[(size_t)((KV0) + kf_ * 16 + l15) * 64 + 32 + l4 * 8];  \
    }                                                                                           \
} while (0)

#define LOADV(VB, KV0) do {                                                                     \
    _Pragma("unroll")                                                                           \
    for (int df_ = 0; df_ < 4; ++df_) {                                                         \
        VB[df_][0] = *(const short8*)&Vh[(size_t)(df_ * 16 + l15) * 2048 + (KV0) + l4 * 8];     \
        VB[df_][1] = *(const short8*)&Vh[(size_t)(df_ * 16 + l15) * 2048 + (KV0) + 32 + l4 * 8];\
    }                                                                                           \
} while (0)

#define TILE(KB, KV0) do {                                                                      \
    const bool diag_ = ((KV0) == (nt - 1) * 64);                                                \
    _Pragma("unroll")                                                                           \
    for (int h_ = 0; h_ < 2; ++h_) {                                                            \
        f32x4 sf_[4];                                                                           \
        __builtin_amdgcn_s_setprio(1);                                                          \
        _Pragma("unroll")                                                                       \
        for (int kf_ = 0; kf_ < 4; ++kf_) {                                                     \
            f32x4 z_ = {};                                                                      \
            z_ = MFMA16(KB[kf_][0], qf[h_][0], z_);                                             \
            z_ = MFMA16(KB[kf_][1], qf[h_][1], z_);                                             \
            sf_[kf_] = z_;                                                                      \
        }                                                                                       \
        __builtin_amdgcn_s_setprio(0);                                                          \
        const int gq_ = q0 + h_ * 16 + l15;                                                     \
        int w_[4][2];                                                                           \
        _Pragma("unroll")                                                                       \
        for (int kf_ = 0; kf_ < 4; ++kf_) {                                                     \
            float pf_[4];                                                                       \
            _Pragma("unroll")                                                                   \
            for (int r_ = 0; r_ < 4; ++r_) {                                                    \
                float v_ = sf_[kf_][r_];                                                        \
                if (diag_ && ((KV0) + kf_ * 16 + l4 * 4 + r_) > gq_) v_ = -1e9f;                \
                float pp_ = exp2f(v_);                                                          \
                lsum[h_] += pp_;                                                                \
                pf_[r_] = pp_;                                                                  \
            }                                                                                   \
            w_[kf_][0] = cvtpk(pf_[0], pf_[1]);                                                 \
            w_[kf_][1] = cvtpk(pf_[2], pf_[3]);                                                 \
        }                                                                                       \
        union { i32x4 i; short8 s8; } pa0_, pa1_;                                               \
        pa0_.i[0] = w_[0][0]; pa0_.i[1] = w_[0][1]; pa0_.i[2] = w_[1][0]; pa0_.i[3] = w_[1][1]; \
        pa1_.i[0] = w_[2][0]; pa1_.i[1] = w_[2][1]; pa1_.i[2] = w_[3][0]; pa1_.i[3] = w_[3][1]; \
        __builtin_amdgcn_s_setprio(1);                                                          \
        _Pragma("unroll")                                                                       \
        for (int df_ = 0; df_ < 4; ++df_) {                                                     \
            o[h_][df_] = MFMA16(pa0_.s8, vb[df_][0], o[h_][df_]);                               \
            o[h_][df_] = MFMA16(pa1_.s8, vb[df_][1], o[h_][df_]);                               \
        }                                                                                       \
        __builtin_amdgcn_s_setprio(0);                                                          \
    }                                                                                           \
} while (0)

__global__ __launch_bounds__(256) void attn_kernel(
    const short* __restrict__ Qg, const short* __restrict__ Kg, const short* __restrict__ Vg,
    short* __restrict__ AO)
{
    const int tid = threadIdx.x, lane = tid & 63, wid = tid >> 6;
    const int l15 = lane & 15, l4 = lane >> 4;
    const int bp = blockIdx.x;            // 0..511
    const int xcd = bp & 7, slot = bp >> 3;   // slot 0..63
    const int bh = xcd * 8 + (slot >> 3);     // 8 heads per XCD (L2 pinning)
    const int iblk = slot & 7;
    const int pr = iblk * 4 + wid;        // pair index 0..31
    const short* Qh = Qg + (size_t)bh * 2048 * 64;
    const short* Kh = Kg + (size_t)bh * 2048 * 64;
    const short* Vh = Vg + (size_t)bh * 64 * 2048;
    const int b = bh >> 4, head = bh & 15;

    for (int half = 0; half < 2; ++half) {
        const int s = half ? (63 - pr) : pr;  // strip 0..63
        const int q0 = s * 32;
        const int nt = (s >> 1) + 1;

        short8 qf[2][2];
        #pragma unroll
        for (int h = 0; h < 2; ++h)
            #pragma unroll
            for (int c = 0; c < 2; ++c)
                qf[h][c] = *(const short8*)&Qh[(size_t)(q0 + h * 16 + l15) * 64 + c * 32 + l4 * 8];

        f32x4 o[2][4] = {};
        float lsum[2] = { 0.f, 0.f };

        short8 kb0[4][2], kb1[4][2], vb[4][2];
        LOADK(kb0, 0);
        int j = 0;
        for (;;) {
            {
                const int kv0 = j * 64;
                if (j + 1 < nt) LOADK(kb1, kv0 + 64);   // issue BEFORE V loads
                LOADV(vb, kv0);
                TILE(kb0, kv0);
            }
            if (++j == nt) break;
            {
                const int kv0 = j * 64;
                if (j + 1 < nt) LOADK(kb0, kv0 + 64);
                LOADV(vb, kv0);
                TILE(kb1, kv0);
            }
            if (++j == nt) break;
        }

        // lsum: sum the 4 k-slice partials (lanes differing in l4)
        #pragma unroll
        for (int h = 0; h < 2; ++h) {
            lsum[h] += __shfl_xor(lsum[h], 16, 64);
            lsum[h] += __shfl_xor(lsum[h], 32, 64);
        }

        // epilogue: O frag is lane -> O[q=l4*4+r][d=df*16+l15]; inv from lane q
        #pragma unroll
        for (int h = 0; h < 2; ++h)
            #pragma unroll
            for (int r = 0; r < 4; ++r) {
                float inv = 1.0f / __shfl(lsum[h], l4 * 4 + r, 64);
                size_t grow = (size_t)b * 2048 + q0 + h * 16 + l4 * 4 + r;
                #pragma unroll
                for (int df = 0; df < 4; ++df)
                    AO[grow * 1024 + head * 64 + df * 16 + l15] = f2bf(o[h][df][r] * inv);
            }
    }
}

// ---------------- out GEMM: AO[8192][1024] @ WoutT[1024][1024]^T + bout -> f32 ----------------
__global__ __launch_bounds__(256) void gemm_out(
    const short* __restrict__ A, const short* __restrict__ Bt,
    const float* __restrict__ bias, float* __restrict__ out)
{
    const int K = 1024;
    __shared__ short As[128 * 32];
    __shared__ short Bs[128 * 32];
    const int tid = threadIdx.x, lane = tid & 63, wid = tid >> 6;
    const int wr = wid >> 1, wc = wid & 1;
    const int m0 = blockIdx.y * 128, n0 = blockIdx.x * 128;
    const int l15 = lane & 15, l4 = lane >> 4;

    f32x4 acc[4][4] = {};

    int rowS[2], ugS[2];
    for (int t = 0; t < 2; ++t) {
        int c = tid + t * 256;
        rowS[t] = c >> 2;
        ugS[t] = (c & 3) ^ ((rowS[t] >> 1) & 3);
    }
    int offA[4], offB[4];
    for (int f = 0; f < 4; ++f) {
        int ra = wr * 64 + f * 16 + l15;
        offA[f] = ra * 32 + ((l4 ^ ((ra >> 1) & 3)) * 8);
        int rb = wc * 64 + f * 16 + l15;
        offB[f] = rb * 32 + ((l4 ^ ((rb >> 1) & 3)) * 8);
    }

    for (int k0 = 0; k0 < K; k0 += 32) {
        __syncthreads();
        for (int t = 0; t < 2; ++t) {
            const short* ga = A  + (size_t)(m0 + rowS[t]) * K + k0 + ugS[t] * 8;
            const short* gb = Bt + (size_t)(n0 + rowS[t]) * K + k0 + ugS[t] * 8;
            short* la = As + (t * 256 + wid * 64) * 8;
            short* lb = Bs + (t * 256 + wid * 64) * 8;
            __builtin_amdgcn_global_load_lds((const __attribute__((address_space(1))) void*)ga,
                                             (__attribute__((address_space(3))) void*)la, 16, 0, 0);
            __builtin_amdgcn_global_load_lds((const __attribute__((address_space(1))) void*)gb,
                                             (__attribute__((address_space(3))) void*)lb, 16, 0, 0);
        }
        __syncthreads();
        short8 a[4], b[4];
        for (int f = 0; f < 4; ++f) a[f] = *(const short8*)&As[offA[f]];
        for (int f = 0; f < 4; ++f) b[f] = *(const short8*)&Bs[offB[f]];
        for (int mf = 0; mf < 4; ++mf)
            for (int nf = 0; nf < 4; ++nf)
                acc[mf][nf] = MFMA16(a[mf], b[nf], acc[mf][nf]);
    }

    for (int mf = 0; mf < 4; ++mf) {
        int grow_base = m0 + wr * 64 + mf * 16 + l4 * 4;
        for (int nf = 0; nf < 4; ++nf) {
            int gcol = n0 + wc * 64 + nf * 16 + l15;
            float bb = bias[gcol];
            for (int r = 0; r < 4; ++r) {
                int grow = grow_base + r;
                out[(size_t)grow * 1024 + gcol] = acc[mf][nf][r] + bb;
            }
        }
    }
}

extern "C" void kernel_launch(void* const* d_in, const int* in_sizes, int n_in,
                              void* d_out, int out_size, void* d_ws, size_t ws_size,
                              hipStream_t stream) {
    (void)in_sizes; (void)n_in; (void)out_size; (void)ws_size;
    const float* x    = (const float*)d_in[0];
    // d_in[1] = attn_mask (causal by construction; applied analytically)
    const float* Wqkv = (const float*)d_in[2];
    const float* bqkv = (const float*)d_in[3];
    const float* Wout = (const float*)d_in[4];
    const float* bout = (const float*)d_in[5];
    float* out = (float*)d_out;

    char* ws = (char*)d_ws;
    short* xb    = (short*)(ws);                         // 16 MB [8192][1024]
    short* WqkvT = (short*)(ws + (16ull << 20));         //  6 MB [3072][1024]
    short* WoutT = (short*)(ws + (22ull << 20));         //  2 MB [1024][1024]
    short* Qg    = (short*)(ws + (24ull << 20));         // 16 MB [64][2048][64]
    short* Kg    = (short*)(ws + (40ull << 20));         // 16 MB [64][2048][64]
    short* Vg    = (short*)(ws + (56ull << 20));         // 16 MB [64][64][2048] (k-permuted)
    short* AO    = xb;                                   // reuse (xb dead after gemm_qkv)

    conv_f32_bf16<<<2048, 256, 0, stream>>>(x, xb, 8192 * 1024 / 4);
    conv_transpose2<<<dim3(3072 / 32, 1024 / 32), dim3(32, 8), 0, stream>>>(Wqkv, WqkvT, 1024, 3072);
    conv_transpose2<<<dim3(1024 / 32, 1024 / 32), dim3(32, 8), 0, stream>>>(Wout, WoutT, 1024, 1024);
    gemm_qkv<<<dim3(24, 64), 256, 0, stream>>>(xb, WqkvT, bqkv, Qg, Kg, Vg);
    attn_kernel<<<512, 256, 0, stream>>>(Qg, Kg, Vg, AO);
    gemm_out<<<dim3(8, 64), 256, 0, stream>>>(AO, WoutT, bout, out);
}

// Round 11
// 312.620 us; speedup vs baseline: 4.0794x; 1.1011x over previous
//
#include <hip/hip_runtime.h>
#include <hip/hip_bf16.h>
#include <stdint.h>

typedef __attribute__((ext_vector_type(8))) short short8;   // 8 bf16 = 4 VGPR (MFMA A/B frag)
typedef __attribute__((ext_vector_type(4))) short short4v;  // 4 bf16
typedef __attribute__((ext_vector_type(4))) float f32x4;    // MFMA C/D frag
typedef __attribute__((ext_vector_type(4))) int   i32x4;

#define MFMA16(a, b, c) __builtin_amdgcn_mfma_f32_16x16x32_bf16((a), (b), (c), 0, 0, 0)

static __device__ __forceinline__ short f2bf(float f) {
    union { float f; uint32_t i; } v; v.f = f;
    uint32_t r = v.i + 0x7fffu + ((v.i >> 16) & 1u);  // RNE
    return (short)(r >> 16);
}

// pack 2 f32 -> 1 u32 of 2 bf16 (lo=a, hi=b), single HW op (T12 recipe)
static __device__ __forceinline__ int cvtpk(float a, float b) {
    int r;
    asm("v_cvt_pk_bf16_f32 %0, %1, %2" : "=v"(r) : "v"(a), "v"(b));
    return r;
}

// ---------------- elementwise f32 -> bf16 (vectorized, G13) ----------------
__global__ void conv_f32_bf16(const float* __restrict__ in, short* __restrict__ out, int n4) {
    int i = blockIdx.x * blockDim.x + threadIdx.x;
    int stride = gridDim.x * blockDim.x;
    for (; i < n4; i += stride) {
        f32x4 v = *(const f32x4*)(in + (size_t)i * 4);
        short4v o;
        o[0] = f2bf(v[0]); o[1] = f2bf(v[1]); o[2] = f2bf(v[2]); o[3] = f2bf(v[3]);
        *(short4v*)(out + (size_t)i * 4) = o;
    }
}

// ------------- transpose + convert: W[R][C] f32 -> Wt[C][R] bf16 -------------
__global__ void conv_transpose2(const float* __restrict__ W, short* __restrict__ Wt, int R, int C) {
    __shared__ float tile[32][33];
    int c0 = blockIdx.x * 32;
    int r0 = blockIdx.y * 32;
    int tx = threadIdx.x;   // 0..31
    int ty = threadIdx.y;   // 0..7
    for (int j = 0; j < 4; ++j) {
        int r = ty * 4 + j;
        tile[r][tx] = W[(size_t)(r0 + r) * C + c0 + tx];
    }
    __syncthreads();
    for (int j = 0; j < 4; ++j) {
        int c = ty * 4 + j;
        Wt[(size_t)(c0 + c) * R + r0 + tx] = f2bf(tile[tx][c]);
    }
}

// ---------------- QKV GEMM: xb[8192][1024] @ WqkvT[3072][1024]^T ----------------
// UNCHANGED (R8/R10 proven). Q pre-scaled by log2(e)/8; V stored k-permuted
// within each 64-row tile: k -> pos = 32c+8a+4b+m (k = 32c+16b+4a+m) to match
// attn's in-lane P k-order. Single compile-time epilogue path (R9 lesson).
__global__ __launch_bounds__(256) void gemm_qkv(
    const short* __restrict__ A, const short* __restrict__ Bt,
    const float* __restrict__ bias,
    short* __restrict__ Qg, short* __restrict__ Kg, short* __restrict__ Vg)
{
    const int K = 1024;
    __shared__ short As[128 * 32];
    __shared__ short Bs[128 * 32];
    const int tid = threadIdx.x, lane = tid & 63, wid = tid >> 6;
    const int wr = wid >> 1, wc = wid & 1;
    const int m0 = blockIdx.y * 128, n0 = blockIdx.x * 128;
    const int l15 = lane & 15, l4 = lane >> 4;

    f32x4 acc[4][4] = {};

    int rowS[2], ugS[2];
    for (int t = 0; t < 2; ++t) {
        int c = tid + t * 256;
        rowS[t] = c >> 2;
        ugS[t] = (c & 3) ^ ((rowS[t] >> 1) & 3);
    }
    int offA[4], offB[4];
    for (int f = 0; f < 4; ++f) {
        int ra = wr * 64 + f * 16 + l15;
        offA[f] = ra * 32 + ((l4 ^ ((ra >> 1) & 3)) * 8);
        int rb = wc * 64 + f * 16 + l15;
        offB[f] = rb * 32 + ((l4 ^ ((rb >> 1) & 3)) * 8);
    }

    for (int k0 = 0; k0 < K; k0 += 32) {
        __syncthreads();
        for (int t = 0; t < 2; ++t) {
            const short* ga = A  + (size_t)(m0 + rowS[t]) * K + k0 + ugS[t] * 8;
            const short* gb = Bt + (size_t)(n0 + rowS[t]) * K + k0 + ugS[t] * 8;
            short* la = As + (t * 256 + wid * 64) * 8;
            short* lb = Bs + (t * 256 + wid * 64) * 8;
            __builtin_amdgcn_global_load_lds((const __attribute__((address_space(1))) void*)ga,
                                             (__attribute__((address_space(3))) void*)la, 16, 0, 0);
            __builtin_amdgcn_global_load_lds((const __attribute__((address_space(1))) void*)gb,
                                             (__attribute__((address_space(3))) void*)lb, 16, 0, 0);
        }
        __syncthreads();
        short8 a[4], b[4];
        for (int f = 0; f < 4; ++f) a[f] = *(const short8*)&As[offA[f]];
        for (int f = 0; f < 4; ++f) b[f] = *(const short8*)&Bs[offB[f]];
        for (int mf = 0; mf < 4; ++mf)
            for (int nf = 0; nf < 4; ++nf)
                acc[mf][nf] = MFMA16(a[mf], b[nf], acc[mf][nf]);
    }

    for (int mf = 0; mf < 4; ++mf) {
        int grow_base = m0 + wr * 64 + mf * 16 + l4 * 4;
        for (int nf = 0; nf < 4; ++nf) {
            int gcol = n0 + wc * 64 + nf * 16 + l15;
            float bb = bias[gcol];
            int which = gcol >> 10, rem = gcol & 1023;
            int h = rem >> 6, d = rem & 63;
            for (int r = 0; r < 4; ++r) {
                int grow = grow_base + r;
                int b = grow >> 11, t = grow & 2047;
                int bh = (b << 4) + h;
                float val = acc[mf][nf][r] + bb;
                if (which == 0) val *= 0.18033688011112042f;  // log2e/8
                short bv = f2bf(val);
                if (which == 0)      Qg[((size_t)bh * 2048 + t) * 64 + d] = bv;
                else if (which == 1) Kg[((size_t)bh * 2048 + t) * 64 + d] = bv;
                else {
                    int k6 = t & 63;
                    int pos = (k6 & 32) + ((k6 & 12) << 1) + ((k6 & 16) >> 2) + (k6 & 3);
                    Vg[((size_t)bh * 64 + d) * 2048 + (t & ~63) + pos] = bv;
                }
            }
        }
    }
}

// ---------------- flash attention: block-cooperative LDS staging ----------------
// Block = (bh, u): q-rows [64u, 64u+64), 4 waves x 16 q-rows SHARING each K/V
// tile (R8's private re-fetch x4 eliminated; block-tiles = 33.8k vs 67.6k
// wave-tiles, each staged once). Double-buffered LDS (2x(8K+8K)=32KB -> ~3
// blocks/CU). Stage via global_load_lds, 2 instr/thread/tile per tensor,
// with G21 both-sides XOR swizzle: linear LDS dest, per-lane inverse-swizzled
// global SOURCE, same XOR on the ds_read address (byte ^= ((row&7)<<4) -> 2-way
// residual conflicts = free). ONE __syncthreads per tile (its implicit
// vmcnt-drain lands ~400cyc after the stage issue -> cheap; catalog 2-phase
// recipe). Wave body = R8's proven swapped-QK^T / in-lane-P / exp2 path,
// V's k-permuted memory layout staged verbatim so PV math is unchanged.
__global__ __launch_bounds__(256) void attn_kernel(
    const short* __restrict__ Qg, const short* __restrict__ Kg, const short* __restrict__ Vg,
    short* __restrict__ AO)
{
    __shared__ __align__(16) short Ks[2][4096];   // [buf][swizzled 64x64 tile]
    __shared__ __align__(16) short Vs[2][4096];
    const int tid = threadIdx.x, lane = tid & 63, wid = tid >> 6;
    const int l15 = lane & 15, l4 = lane >> 4;
    const int bp = blockIdx.x;                 // 0..2047
    const int xcd = bp & 7, slot = bp >> 3;    // slot 0..255
    const int bh = xcd * 8 + (slot >> 5);      // 8 heads per XCD (L2 pinning)
    const int u  = 31 - (slot & 31);           // big-u blocks dispatch first
    const short* Qh = Qg + (size_t)bh * 2048 * 64;
    const short* Kh = Kg + (size_t)bh * 2048 * 64;
    const short* Vh = Vg + (size_t)bh * 64 * 2048;
    const int b = bh >> 4, head = bh & 15;
    const int q0 = u * 64;
    const int nt = u + 1;

    // stage tile JJ into buffer BB: per-lane swizzled source, linear LDS dest
#define STAGE(JJ, BB) do {                                                                       \
    const int kv0_ = (JJ) * 64;                                                                  \
    _Pragma("unroll")                                                                            \
    for (int i_ = 0; i_ < 2; ++i_) {                                                             \
        int L_ = i_ * 4096 + wid * 1024 + lane * 16;       /* lds byte 0..8191 */                \
        int G_ = L_ ^ (((L_ >> 7) & 7) << 4);              /* involution */                      \
        const char* ksrc = (const char*)Kh + (size_t)kv0_ * 128 + G_;                            \
        short* kdst = &Ks[BB][0] + (i_ * 2048 + wid * 512);                                      \
        __builtin_amdgcn_global_load_lds((const __attribute__((address_space(1))) void*)ksrc,    \
                                         (__attribute__((address_space(3))) void*)kdst, 16, 0, 0);\
        const char* vsrc = (const char*)Vh + (size_t)(G_ >> 7) * 4096 + (size_t)kv0_ * 2 + (G_ & 127);\
        short* vdst = &Vs[BB][0] + (i_ * 2048 + wid * 512);                                      \
        __builtin_amdgcn_global_load_lds((const __attribute__((address_space(1))) void*)vsrc,    \
                                         (__attribute__((address_space(3))) void*)vdst, 16, 0, 0);\
    }                                                                                            \
} while (0)

    // per-wave Q frags (16 q-rows)
    short8 qf[2];
    #pragma unroll
    for (int c = 0; c < 2; ++c)
        qf[c] = *(const short8*)&Qh[(size_t)(q0 + wid * 16 + l15) * 64 + c * 32 + l4 * 8];

    f32x4 o[4] = {};
    float lsum = 0.f;
    const int gq = q0 + wid * 16 + l15;

    STAGE(0, 0);
    __syncthreads();

    int cur = 0;
    for (int j = 0; j < nt; ++j) {
        if (j + 1 < nt) STAGE(j + 1, cur ^ 1);
        const int kv0 = j * 64;
        const bool diag = (j == nt - 1);

        // frag reads from swizzled LDS
        short8 kb[4][2], vb[4][2];
        #pragma unroll
        for (int kf = 0; kf < 4; ++kf)
            #pragma unroll
            for (int c = 0; c < 2; ++c) {
                int rowK = kf * 16 + l15;
                int A = rowK * 128 + c * 64 + l4 * 16;
                kb[kf][c] = *(const short8*)((const char*)&Ks[cur][0] + (A ^ ((rowK & 7) << 4)));
            }
        #pragma unroll
        for (int df = 0; df < 4; ++df)
            #pragma unroll
            for (int c = 0; c < 2; ++c) {
                int rowV = df * 16 + l15;
                int A = rowV * 128 + c * 64 + l4 * 16;
                vb[df][c] = *(const short8*)((const char*)&Vs[cur][0] + (A ^ ((rowV & 7) << 4)));
            }

        // S^T = K·Q^T : lane -> S[k=kv0+kf*16+l4*4+r][q=l15]
        f32x4 sf[4];
        #pragma unroll
        for (int kf = 0; kf < 4; ++kf) {
            f32x4 z = {};
            z = MFMA16(kb[kf][0], qf[0], z);
            z = MFMA16(kb[kf][1], qf[1], z);
            sf[kf] = z;
        }
        int w[4][2];
        #pragma unroll
        for (int kf = 0; kf < 4; ++kf) {
            float pf[4];
            #pragma unroll
            for (int r = 0; r < 4; ++r) {
                float v = sf[kf][r];
                if (diag && (kv0 + kf * 16 + l4 * 4 + r) > gq) v = -1e9f;
                float pp = exp2f(v);
                lsum += pp;
                pf[r] = pp;
            }
            w[kf][0] = cvtpk(pf[0], pf[1]);
            w[kf][1] = cvtpk(pf[2], pf[3]);
        }
        union { i32x4 i; short8 s8; } pa0, pa1;
        pa0.i[0] = w[0][0]; pa0.i[1] = w[0][1]; pa0.i[2] = w[1][0]; pa0.i[3] = w[1][1];
        pa1.i[0] = w[2][0]; pa1.i[1] = w[2][1]; pa1.i[2] = w[3][0]; pa1.i[3] = w[3][1];
        #pragma unroll
        for (int df = 0; df < 4; ++df) {
            o[df] = MFMA16(pa0.s8, vb[df][0], o[df]);
            o[df] = MFMA16(pa1.s8, vb[df][1], o[df]);
        }

        __syncthreads();   // drains stage(j+1) vmcnt + protects buffer swap
        cur ^= 1;
    }

    // lsum: sum the 4 k-slice partials (lanes differing in l4)
    lsum += __shfl_xor(lsum, 16, 64);
    lsum += __shfl_xor(lsum, 32, 64);

    // epilogue: O frag lane -> O[q=l4*4+r][d=df*16+l15]; inv from lane q
    #pragma unroll
    for (int r = 0; r < 4; ++r) {
        float inv = 1.0f / __shfl(lsum, l4 * 4 + r, 64);
        size_t grow = (size_t)b * 2048 + q0 + wid * 16 + l4 * 4 + r;
        #pragma unroll
        for (int df = 0; df < 4; ++df)
            AO[grow * 1024 + head * 64 + df * 16 + l15] = f2bf(o[df][r] * inv);
    }
#undef STAGE
}

// ---------------- out GEMM: AO[8192][1024] @ WoutT[1024][1024]^T + bout -> f32 ----------------
__global__ __launch_bounds__(256) void gemm_out(
    const short* __restrict__ A, const short* __restrict__ Bt,
    const float* __restrict__ bias, float* __restrict__ out)
{
    const int K = 1024;
    __shared__ short As[128 * 32];
    __shared__ short Bs[128 * 32];
    const int tid = threadIdx.x, lane = tid & 63, wid = tid >> 6;
    const int wr = wid >> 1, wc = wid & 1;
    const int m0 = blockIdx.y * 128, n0 = blockIdx.x * 128;
    const int l15 = lane & 15, l4 = lane >> 4;

    f32x4 acc[4][4] = {};

    int rowS[2], ugS[2];
    for (int t = 0; t < 2; ++t) {
        int c = tid + t * 256;
        rowS[t] = c >> 2;
        ugS[t] = (c & 3) ^ ((rowS[t] >> 1) & 3);
    }
    int offA[4], offB[4];
    for (int f = 0; f < 4; ++f) {
        int ra = wr * 64 + f * 16 + l15;
        offA[f] = ra * 32 + ((l4 ^ ((ra >> 1) & 3)) * 8);
        int rb = wc * 64 + f * 16 + l15;
        offB[f] = rb * 32 + ((l4 ^ ((rb >> 1) & 3)) * 8);
    }

    for (int k0 = 0; k0 < K; k0 += 32) {
        __syncthreads();
        for (int t = 0; t < 2; ++t) {
            const short* ga = A  + (size_t)(m0 + rowS[t]) * K + k0 + ugS[t] * 8;
            const short* gb = Bt + (size_t)(n0 + rowS[t]) * K + k0 + ugS[t] * 8;
            short* la = As + (t * 256 + wid * 64) * 8;
            short* lb = Bs + (t * 256 + wid * 64) * 8;
            __builtin_amdgcn_global_load_lds((const __attribute__((address_space(1))) void*)ga,
                                             (__attribute__((address_space(3))) void*)la, 16, 0, 0);
            __builtin_amdgcn_global_load_lds((const __attribute__((address_space(1))) void*)gb,
                                             (__attribute__((address_space(3))) void*)lb, 16, 0, 0);
        }
        __syncthreads();
        short8 a[4], b[4];
        for (int f = 0; f < 4; ++f) a[f] = *(const short8*)&As[offA[f]];
        for (int f = 0; f < 4; ++f) b[f] = *(const short8*)&Bs[offB[f]];
        for (int mf = 0; mf < 4; ++mf)
            for (int nf = 0; nf < 4; ++nf)
                acc[mf][nf] = MFMA16(a[mf], b[nf], acc[mf][nf]);
    }

    for (int mf = 0; mf < 4; ++mf) {
        int grow_base = m0 + wr * 64 + mf * 16 + l4 * 4;
        for (int nf = 0; nf < 4; ++nf) {
            int gcol = n0 + wc * 64 + nf * 16 + l15;
            float bb = bias[gcol];
            for (int r = 0; r < 4; ++r) {
                int grow = grow_base + r;
                out[(size_t)grow * 1024 + gcol] = acc[mf][nf][r] + bb;
            }
        }
    }
}

extern "C" void kernel_launch(void* const* d_in, const int* in_sizes, int n_in,
                              void* d_out, int out_size, void* d_ws, size_t ws_size,
                              hipStream_t stream) {
    (void)in_sizes; (void)n_in; (void)out_size; (void)ws_size;
    const float* x    = (const float*)d_in[0];
    // d_in[1] = attn_mask (causal by construction; applied analytically)
    const float* Wqkv = (const float*)d_in[2];
    const float* bqkv = (const float*)d_in[3];
    const float* Wout = (const float*)d_in[4];
    const float* bout = (const float*)d_in[5];
    float* out = (float*)d_out;

    char* ws = (char*)d_ws;
    short* xb    = (short*)(ws);                         // 16 MB [8192][1024]
    short* WqkvT = (short*)(ws + (16ull << 20));         //  6 MB [3072][1024]
    short* WoutT = (short*)(ws + (22ull << 20));         //  2 MB [1024][1024]
    short* Qg    = (short*)(ws + (24ull << 20));         // 16 MB [64][2048][64]
    short* Kg    = (short*)(ws + (40ull << 20));         // 16 MB [64][2048][64]
    short* Vg    = (short*)(ws + (56ull << 20));         // 16 MB [64][64][2048] (k-permuted)
    short* AO    = xb;                                   // reuse (xb dead after gemm_qkv)

    conv_f32_bf16<<<2048, 256, 0, stream>>>(x, xb, 8192 * 1024 / 4);
    conv_transpose2<<<dim3(3072 / 32, 1024 / 32), dim3(32, 8), 0, stream>>>(Wqkv, WqkvT, 1024, 3072);
    conv_transpose2<<<dim3(1024 / 32, 1024 / 32), dim3(32, 8), 0, stream>>>(Wout, WoutT, 1024, 1024);
    gemm_qkv<<<dim3(24, 64), 256, 0, stream>>>(xb, WqkvT, bqkv, Qg, Kg, Vg);
    attn_kernel<<<2048, 256, 0, stream>>>(Qg, Kg, Vg, AO);
    gemm_out<<<dim3(8, 64), 256, 0, stream>>>(AO, WoutT, bout, out);
}